// Round 10
// baseline (327.037 us; speedup 1.0000x reference)
//
#include <hip/hip_runtime.h>

#define HIDDEN 2048
#define NHEADS 32
#define NKV 8
#define HD 64
#define BATCH 2
#define SEQ 2048
#define KVD 512    // NKV*HD
#define BSZ 4096   // BATCH*SEQ
#define QKVD 3072  // HIDDEN + 2*KVD

typedef __bf16 bfx8 __attribute__((ext_vector_type(8)));
typedef __bf16 bfx4 __attribute__((ext_vector_type(4)));
typedef __bf16 bfx2 __attribute__((ext_vector_type(2)));
typedef float f32x4 __attribute__((ext_vector_type(4)));
typedef unsigned int ux4 __attribute__((ext_vector_type(4)));

// Q pre-scale folded into Wq/bq: exp(s/8) = 2^(s*0.125*log2e)
#define QSCALE 0.1803368801111204f

// async global->LDS, 16B per lane. LDS dest is wave-uniform base; HW adds lane*16.
__device__ __forceinline__ void gl_lds16(const __bf16* g, __bf16* l) {
    __builtin_amdgcn_global_load_lds(
        (const __attribute__((address_space(1))) unsigned int*)g,
        (__attribute__((address_space(3))) unsigned int*)l, 16, 0, 0);
}

// pack two f32 -> one u32 of 2x bf16 (compiler emits v_cvt_pk_bf16_f32)
__device__ __forceinline__ unsigned int pk2(float lo, float hi) {
    bfx2 v = {(__bf16)lo, (__bf16)hi};
    return __builtin_bit_cast(unsigned int, v);
}

// ---------------- f32 -> bf16 convert (x) ----------------
__global__ __launch_bounds__(256) void cvt_bf16(const float* __restrict__ src,
                                                __bf16* __restrict__ dst, int n4) {
    int i = blockIdx.x * 256 + threadIdx.x;
    if (i >= n4) return;
    float4 f = ((const float4*)src)[i];
    bfx4 o = {(__bf16)f.x, (__bf16)f.y, (__bf16)f.z, (__bf16)f.w};
    *(bfx4*)(dst + (size_t)i * 4) = o;
}

// ------------- one 64x64 tile: src f32 [R,C] -> dst bf16 [C,R], *mul -------------
__device__ __forceinline__ void tcvt_tile(const float* __restrict__ src,
                                          __bf16* __restrict__ dst,
                                          int R, int C, int tx, int ty,
                                          float (*tile)[65], int t, float mul) {
    int br = ty * 64, bc = tx * 64;
    {
        int r = t >> 4, c = (t & 15) * 4;
#pragma unroll
        for (int i = 0; i < 4; ++i) {
            float4 v = *(const float4*)(&src[(long)(br + r + i * 16) * C + bc + c]);
            tile[r + i * 16][c + 0] = v.x * mul;
            tile[r + i * 16][c + 1] = v.y * mul;
            tile[r + i * 16][c + 2] = v.z * mul;
            tile[r + i * 16][c + 3] = v.w * mul;
        }
    }
    __syncthreads();
    {
        int d = t >> 2, tt0 = (t & 3) * 16;
        bfx8 o0, o1;
#pragma unroll
        for (int j = 0; j < 8; ++j) o0[j] = (__bf16)tile[tt0 + j][d];
#pragma unroll
        for (int j = 0; j < 8; ++j) o1[j] = (__bf16)tile[tt0 + 8 + j][d];
        *(bfx8*)(&dst[(long)(bc + d) * R + br + tt0]) = o0;
        *(bfx8*)(&dst[(long)(bc + d) * R + br + tt0 + 8]) = o1;
    }
}

// --------- fused prep: all 4 weight transposes + bias concat, one launch ---------
__global__ __launch_bounds__(256) void prep(const float* __restrict__ Wq,
                                            const float* __restrict__ Wk,
                                            const float* __restrict__ Wv,
                                            const float* __restrict__ Wo,
                                            const float* __restrict__ bq,
                                            const float* __restrict__ bk,
                                            const float* __restrict__ bv,
                                            __bf16* __restrict__ wqkvt,
                                            __bf16* __restrict__ wot,
                                            float* __restrict__ bqkv) {
    __shared__ float tile[64][65];
    int idx = blockIdx.x, t = threadIdx.x;
    if (idx < 1024) {
        tcvt_tile(Wq, wqkvt, HIDDEN, HIDDEN, idx & 31, idx >> 5, tile, t, QSCALE);
    } else if (idx < 1280) {
        int l = idx - 1024;
        tcvt_tile(Wk, wqkvt + (size_t)HIDDEN * HIDDEN, HIDDEN, KVD, l & 7, l >> 3, tile, t, 1.0f);
    } else if (idx < 1536) {
        int l = idx - 1280;
        tcvt_tile(Wv, wqkvt + (size_t)(HIDDEN + KVD) * HIDDEN, HIDDEN, KVD, l & 7, l >> 3, tile, t, 1.0f);
    } else if (idx < 2560) {
        int l = idx - 1536;
        tcvt_tile(Wo, wot, HIDDEN, HIDDEN, l & 31, l >> 5, tile, t, 1.0f);
    } else {
        int i = (idx - 2560) * 256 + t;
        if (i < QKVD) {
            float v = (i < HIDDEN) ? bq[i] * QSCALE
                                   : (i < HIDDEN + KVD ? bk[i - HIDDEN] : bv[i - HIDDEN - KVD]);
            bqkv[i] = v;
        }
    }
}

// ------------- V slice of qkv -> vt [B*NKV][HD][SEQ] -------------
__global__ __launch_bounds__(256) void transpose_v(const __bf16* __restrict__ qkv,
                                                   __bf16* __restrict__ vt) {
    __shared__ __bf16 tile[64][65];
    int t = threadIdx.x;
    int nb0 = blockIdx.x * 64;
    int bh = blockIdx.y;  // b*NKV + kv
    int b = bh >> 3, kv = bh & 7;
    {
        int tt = t >> 2, c0 = (t & 3) * 16;
        const __bf16* p = &qkv[(long)(b * SEQ + nb0 + tt) * QKVD + HIDDEN + KVD + kv * HD + c0];
        bfx8 a0 = *(const bfx8*)(p);
        bfx8 a1 = *(const bfx8*)(p + 8);
#pragma unroll
        for (int j = 0; j < 8; ++j) tile[tt][c0 + j] = a0[j];
#pragma unroll
        for (int j = 0; j < 8; ++j) tile[tt][c0 + 8 + j] = a1[j];
    }
    __syncthreads();
    {
        int d = t >> 2, tt0 = (t & 3) * 16;
        bfx8 o0, o1;
#pragma unroll
        for (int j = 0; j < 8; ++j) o0[j] = tile[tt0 + j][d];
#pragma unroll
        for (int j = 0; j < 8; ++j) o1[j] = tile[tt0 + 8 + j][d];
        __bf16* q = &vt[((long)bh * HD + d) * SEQ + nb0 + tt0];
        *(bfx8*)(q) = o0;
        *(bfx8*)(q + 8) = o1;
    }
}

// ------- GEMM: C[M,N] = A[M,K] * Bt[N,K]^T + bias, 128x128 tile, 16x16x32 MFMA --------
// (32x32x16 variant tested R9: neutral-to-negative — the binding constraint is the
// barrier-drain structure, not matrix-pipe rate or LDS reads. Reverted.)
// 1-barrier dbuf K-loop + DMA prefetch. Staging lanes XOR-permute the 8-elem
// col-blocks so fragment reads are bank-conflict-free.
// R10 experiment: __launch_bounds__(256,4) — cap VGPRs at 128 to lift occupancy
// from 3 to 4 blocks/CU (LDS limit is 5 at 32KB). 16 waves/CU was empirically the
// attn sweet spot for covering the barrier drain; apply the same to gemm.
template <bool OUT_BF16>
__global__ __launch_bounds__(256, 4) void gemm128(const __bf16* __restrict__ A,
                                                  const __bf16* __restrict__ Bt,
                                                  const float* __restrict__ bias,
                                                  void* __restrict__ C,
                                                  int M, int N, int K) {
    __shared__ __align__(16) __bf16 As[2][128 * 32];
    __shared__ __align__(16) __bf16 Bs[2][128 * 32];
    int t = threadIdx.x;
    int w = t >> 6, lane = t & 63;
    int lrow = lane & 15, quad = lane >> 4;
    long m0 = (long)blockIdx.y * 128, n0 = (long)blockIdx.x * 128;
    int wr = (w >> 1) * 64, wc = (w & 1) * 64;
    f32x4 acc[4][4] = {};
    int srow = t >> 2, scol = (((t & 3) ^ ((t >> 3) & 3))) * 8;  // staging swizzle
    int sA = (lrow >> 1) & 3;                                    // read-side selector
    const __bf16* Ag = A + (m0 + srow) * (long)K + scol;
    const __bf16* Bg = Bt + (n0 + srow) * (long)K + scol;
#define STAGE_G(kb, buf)                                                      \
    {                                                                         \
        _Pragma("unroll") for (int c = 0; c < 2; ++c) {                       \
            gl_lds16(Ag + (long)c * 64 * K + (kb), &As[buf][c * 2048 + w * 512]); \
            gl_lds16(Bg + (long)c * 64 * K + (kb), &Bs[buf][c * 2048 + w * 512]); \
        }                                                                     \
    }
    STAGE_G(0, 0);
    int nk = K >> 5;
    for (int it = 0; it < nk; ++it) {
        __syncthreads();  // drains prev-iter prefetch; all waves done with other buffer
        if (it + 1 < nk) STAGE_G((it + 1) * 32, (it + 1) & 1);
        const __bf16* Ab = &As[it & 1][0];
        const __bf16* Bb = &Bs[it & 1][0];
        bfx8 af[4], bfr[4];
#pragma unroll
        for (int i = 0; i < 4; ++i)
            af[i] = *(const bfx8*)&Ab[(wr + i * 16 + lrow) * 32 + ((quad ^ sA) * 8)];
#pragma unroll
        for (int j = 0; j < 4; ++j)
            bfr[j] = *(const bfx8*)&Bb[(wc + j * 16 + lrow) * 32 + ((quad ^ sA) * 8)];
#pragma unroll
        for (int i = 0; i < 4; ++i)
#pragma unroll
            for (int j = 0; j < 4; ++j)
                acc[i][j] = __builtin_amdgcn_mfma_f32_16x16x32_bf16(af[i], bfr[j], acc[i][j], 0, 0, 0);
    }
#undef STAGE_G
#pragma unroll
    for (int j = 0; j < 4; ++j) {
        long col = n0 + wc + j * 16 + lrow;
        float bv = bias[col];
#pragma unroll
        for (int i = 0; i < 4; ++i) {
#pragma unroll
            for (int r = 0; r < 4; ++r) {
                long row = m0 + wr + i * 16 + quad * 4 + r;
                float val = acc[i][j][r] + bv;
                if (OUT_BF16)
                    ((__bf16*)C)[row * N + col] = (__bf16)val;
                else
                    ((float*)C)[row * N + col] = val;
            }
        }
    }
}

// ---------------- attention v8 (champion, frozen): 32 q/wave + T5 setprio ----------------
// 16 waves/CU is the empirically-best occupancy (64q/wave tested 3 ways: 93.5-94 µs vs
// 86.5 here). Full-rate x32 QK^T and PV, permlane-swap P^T repack, LDS dbuf DMA staging.
__global__ __launch_bounds__(256, 4) void attn(const __bf16* __restrict__ QKV,  // [BSZ,QKVD]
                                               const __bf16* __restrict__ Vt,   // [B*NKV][HD][SEQ]
                                               __bf16* __restrict__ O) {        // [BSZ,HIDDEN]
    __shared__ __align__(16) __bf16 Ks[2][64 * 64];
    __shared__ __align__(16) __bf16 Vs[2][64 * 64];
    int t = threadIdx.x;
    int w = t >> 6, lane = t & 63;
    int lrow = lane & 15, quad = lane >> 4;
    int qb = blockIdx.x, bh = blockIdx.y;
    int b = bh >> 5, h = bh & 31, kv = h >> 2;
    int q0 = qb * 128 + w * 32;  // first q-row of this wave

    // Q fragments (B operand: n=q=lane&15, k=quad*8+j)
    bfx8 qf[2][2];
#pragma unroll
    for (int i = 0; i < 2; ++i)
#pragma unroll
        for (int kk = 0; kk < 2; ++kk)
            qf[i][kk] = *(const bfx8*)(QKV + (long)(b * SEQ + q0 + i * 16 + lrow) * QKVD +
                                       h * HD + kk * 32 + quad * 8);

    int srow = t >> 2, scol = (((t & 3) ^ ((t >> 3) & 3))) * 8;  // staging swizzle
    int sA = (lrow >> 1) & 3;                                    // read-side selector
    const __bf16* kg = QKV + (long)(b * SEQ + srow) * QKVD + HIDDEN + kv * HD + scol;
    const __bf16* vg = Vt + ((long)(b * NKV + kv) * HD + srow) * SEQ + scol;
#define STAGE_KV(nb, buf)                                                          \
    {                                                                              \
        _Pragma("unroll") for (int c = 0; c < 2; ++c) {                            \
            gl_lds16(kg + (long)(nb)*QKVD + c * 32, &Ks[buf][c * 2048 + w * 512]); \
            gl_lds16(vg + (nb) + c * 32, &Vs[buf][c * 2048 + w * 512]);            \
        }                                                                          \
    }
    STAGE_KV(0, 0);

    f32x4 accO[4][2] = {};  // [dtile][qtile]; lane=q(lane&15), d = quad*4 + reg
    float lacc[2] = {0.f, 0.f};

    for (int it = 0; it < SEQ / 64; ++it) {
        __syncthreads();  // drains this chunk's DMA; all waves done with other buffer
        if (it + 1 < SEQ / 64) STAGE_KV((it + 1) * 64, (it + 1) & 1);
        const __bf16* Kb = &Ks[it & 1][0];
        const __bf16* Vb = &Vs[it & 1][0];
#pragma unroll
        for (int ch = 0; ch < 2; ++ch) {  // 32-key chunk = key tiles 2ch, 2ch+1
            f32x4 s2[2][2];               // [tile-in-pair][qtile]
#pragma unroll
            for (int tp = 0; tp < 2; ++tp) {
                int tt = ch * 2 + tp;
                bfx8 ka0 = *(const bfx8*)&Kb[tt * 512 + lrow * 32 + ((quad ^ sA) * 8)];
                bfx8 ka1 = *(const bfx8*)&Kb[2048 + tt * 512 + lrow * 32 + ((quad ^ sA) * 8)];
                __builtin_amdgcn_s_setprio(1);
#pragma unroll
                for (int i = 0; i < 2; ++i) {
                    f32x4 z = {};
                    z = __builtin_amdgcn_mfma_f32_16x16x32_bf16(ka0, qf[i][0], z, 0, 0, 0);
                    s2[tp][i] = __builtin_amdgcn_mfma_f32_16x16x32_bf16(ka1, qf[i][1], z, 0, 0, 0);
                }
                __builtin_amdgcn_s_setprio(0);
            }
            // exp2 + row-sum + pack P^T into x32 fragments (one per q-tile)
            bfx8 p8v[2];
#pragma unroll
            for (int i = 0; i < 2; ++i) {
                float pa0 = __builtin_amdgcn_exp2f(s2[0][i][0]);
                float pa1 = __builtin_amdgcn_exp2f(s2[0][i][1]);
                float pa2 = __builtin_amdgcn_exp2f(s2[0][i][2]);
                float pa3 = __builtin_amdgcn_exp2f(s2[0][i][3]);
                float pb0 = __builtin_amdgcn_exp2f(s2[1][i][0]);
                float pb1 = __builtin_amdgcn_exp2f(s2[1][i][1]);
                float pb2 = __builtin_amdgcn_exp2f(s2[1][i][2]);
                float pb3 = __builtin_amdgcn_exp2f(s2[1][i][3]);
                lacc[i] += ((pa0 + pa1) + (pa2 + pa3)) + ((pb0 + pb1) + (pb2 + pb3));
                unsigned int A0 = pk2(pa0, pa1), A1 = pk2(pa2, pa3);
                unsigned int B0 = pk2(pb0, pb1), B1 = pk2(pb2, pb3);
                asm("v_permlane32_swap_b32 %0, %1" : "+v"(A0), "+v"(B0));
                asm("v_permlane16_swap_b32 %0, %1" : "+v"(A0), "+v"(B0));
                asm("v_permlane32_swap_b32 %0, %1" : "+v"(A1), "+v"(B1));
                asm("v_permlane16_swap_b32 %0, %1" : "+v"(A1), "+v"(B1));
                ux4 pw = {A0, A1, B0, B1};  // = {w0, w1, w2, w3}
                p8v[i] = __builtin_bit_cast(bfx8, pw);
            }
            // V a-frags: m=d=lane&15, k = quad*8+j -> same b128 pattern as K
#pragma unroll
            for (int dt = 0; dt < 4; ++dt) {
                bfx8 va = *(const bfx8*)&Vb[ch * 2048 + (dt * 16 + lrow) * 32 + ((quad ^ sA) * 8)];
                __builtin_amdgcn_s_setprio(1);
#pragma unroll
                for (int i = 0; i < 2; ++i)
                    accO[dt][i] = __builtin_amdgcn_mfma_f32_16x16x32_bf16(va, p8v[i], accO[dt][i], 0, 0, 0);
                __builtin_amdgcn_s_setprio(0);
            }
        }
    }
    // ---- epilogue: cross-quad l reduction, normalize, packed b64 stores ----
    float inv[2];
#pragma unroll
    for (int i = 0; i < 2; ++i) {
        float l = lacc[i];
        l += __shfl_xor(l, 16);
        l += __shfl_xor(l, 32);
        inv[i] = 1.0f / l;
    }
#pragma unroll
    for (int i = 0; i < 2; ++i) {
        long row = (long)(b * SEQ + q0 + i * 16 + lrow);
#pragma unroll
        for (int dt = 0; dt < 4; ++dt) {
            bfx4 o4 = {(__bf16)(accO[dt][i][0] * inv[i]), (__bf16)(accO[dt][i][1] * inv[i]),
                       (__bf16)(accO[dt][i][2] * inv[i]), (__bf16)(accO[dt][i][3] * inv[i])};
            *(bfx4*)&O[row * HIDDEN + h * HD + dt * 16 + quad * 4] = o4;
        }
    }
#undef STAGE_KV
}

extern "C" void kernel_launch(void* const* d_in, const int* in_sizes, int n_in,
                              void* d_out, int out_size, void* d_ws, size_t ws_size,
                              hipStream_t stream) {
    const float* x  = (const float*)d_in[0];
    const float* Wq = (const float*)d_in[1];
    const float* bq = (const float*)d_in[2];
    const float* Wk = (const float*)d_in[3];
    const float* bk = (const float*)d_in[4];
    const float* Wv = (const float*)d_in[5];
    const float* bv = (const float*)d_in[6];
    const float* Wo = (const float*)d_in[7];
    const float* bo = (const float*)d_in[8];
    float* out = (float*)d_out;

    __bf16* ws    = (__bf16*)d_ws;
    __bf16* xb    = ws;                                   // [BSZ, HIDDEN]
    __bf16* wqkvt = xb + (size_t)BSZ * HIDDEN;            // [QKVD, HIDDEN] (N,K)
    __bf16* wot   = wqkvt + (size_t)QKVD * HIDDEN;        // [HIDDEN, HIDDEN]
    __bf16* qkv   = wot + (size_t)HIDDEN * HIDDEN;        // [BSZ, QKVD]
    __bf16* vt_   = qkv + (size_t)BSZ * QKVD;             // [B*NKV][HD][SEQ]
    __bf16* ab_   = vt_ + (size_t)BSZ * KVD;              // [BSZ, HIDDEN]
    float*  bqkv  = (float*)(ab_ + (size_t)BSZ * HIDDEN); // [QKVD]

    cvt_bf16<<<(BSZ * HIDDEN / 4 + 255) / 256, 256, 0, stream>>>(x, xb, BSZ * HIDDEN / 4);
    prep<<<2560 + (QKVD + 255) / 256, 256, 0, stream>>>(Wq, Wk, Wv, Wo, bq, bk, bv,
                                                        wqkvt, wot, bqkv);

    gemm128<true><<<dim3(QKVD / 128, BSZ / 128), 256, 0, stream>>>(xb, wqkvt, bqkv, qkv, BSZ, QKVD, HIDDEN);

    transpose_v<<<dim3(SEQ / 64, BATCH * NKV), 256, 0, stream>>>(qkv, vt_);
    attn<<<dim3(SEQ / 128, BATCH * NHEADS), 256, 0, stream>>>(qkv, vt_, ab_);

    gemm128<false><<<dim3(HIDDEN / 128, BSZ / 128), 256, 0, stream>>>(ab_, wot, bo, out, BSZ, HIDDEN, HIDDEN);
}

// Round 11
// 312.676 us; speedup vs baseline: 1.0459x; 1.0459x over previous
//
#include <hip/hip_runtime.h>

#define HIDDEN 2048
#define NHEADS 32
#define NKV 8
#define HD 64
#define BATCH 2
#define SEQ 2048
#define KVD 512    // NKV*HD
#define BSZ 4096   // BATCH*SEQ
#define QKVD 3072  // HIDDEN + 2*KVD

typedef __bf16 bfx8 __attribute__((ext_vector_type(8)));
typedef __bf16 bfx4 __attribute__((ext_vector_type(4)));
typedef __bf16 bfx2 __attribute__((ext_vector_type(2)));
typedef float f32x4 __attribute__((ext_vector_type(4)));
typedef unsigned int ux4 __attribute__((ext_vector_type(4)));

// Q pre-scale folded into Wq/bq: exp(s/8) = 2^(s*0.125*log2e)
#define QSCALE 0.1803368801111204f

// async global->LDS, 16B per lane. LDS dest is wave-uniform base; HW adds lane*16.
__device__ __forceinline__ void gl_lds16(const __bf16* g, __bf16* l) {
    __builtin_amdgcn_global_load_lds(
        (const __attribute__((address_space(1))) unsigned int*)g,
        (__attribute__((address_space(3))) unsigned int*)l, 16, 0, 0);
}

// pack two f32 -> one u32 of 2x bf16 (compiler emits v_cvt_pk_bf16_f32)
__device__ __forceinline__ unsigned int pk2(float lo, float hi) {
    bfx2 v = {(__bf16)lo, (__bf16)hi};
    return __builtin_bit_cast(unsigned int, v);
}

// ------------- one 64x64 tile: src f32 [R,C] -> dst bf16 [C,R], *mul -------------
__device__ __forceinline__ void tcvt_tile(const float* __restrict__ src,
                                          __bf16* __restrict__ dst,
                                          int R, int C, int tx, int ty,
                                          float (*tile)[65], int t, float mul) {
    int br = ty * 64, bc = tx * 64;
    {
        int r = t >> 4, c = (t & 15) * 4;
#pragma unroll
        for (int i = 0; i < 4; ++i) {
            float4 v = *(const float4*)(&src[(long)(br + r + i * 16) * C + bc + c]);
            tile[r + i * 16][c + 0] = v.x * mul;
            tile[r + i * 16][c + 1] = v.y * mul;
            tile[r + i * 16][c + 2] = v.z * mul;
            tile[r + i * 16][c + 3] = v.w * mul;
        }
    }
    __syncthreads();
    {
        int d = t >> 2, tt0 = (t & 3) * 16;
        bfx8 o0, o1;
#pragma unroll
        for (int j = 0; j < 8; ++j) o0[j] = (__bf16)tile[tt0 + j][d];
#pragma unroll
        for (int j = 0; j < 8; ++j) o1[j] = (__bf16)tile[tt0 + 8 + j][d];
        *(bfx8*)(&dst[(long)(bc + d) * R + br + tt0]) = o0;
        *(bfx8*)(&dst[(long)(bc + d) * R + br + tt0 + 8]) = o1;
    }
}

// --- fused prep: 4 weight transposes + bias concat + x f32->bf16 cvt, one launch ---
__global__ __launch_bounds__(256) void prep(const float* __restrict__ x,
                                            const float* __restrict__ Wq,
                                            const float* __restrict__ Wk,
                                            const float* __restrict__ Wv,
                                            const float* __restrict__ Wo,
                                            const float* __restrict__ bq,
                                            const float* __restrict__ bk,
                                            const float* __restrict__ bv,
                                            __bf16* __restrict__ xb,
                                            __bf16* __restrict__ wqkvt,
                                            __bf16* __restrict__ wot,
                                            float* __restrict__ bqkv) {
    __shared__ float tile[64][65];
    int idx = blockIdx.x, t = threadIdx.x;
    if (idx < 1024) {
        tcvt_tile(Wq, wqkvt, HIDDEN, HIDDEN, idx & 31, idx >> 5, tile, t, QSCALE);
    } else if (idx < 1280) {
        int l = idx - 1024;
        tcvt_tile(Wk, wqkvt + (size_t)HIDDEN * HIDDEN, HIDDEN, KVD, l & 7, l >> 3, tile, t, 1.0f);
    } else if (idx < 1536) {
        int l = idx - 1280;
        tcvt_tile(Wv, wqkvt + (size_t)(HIDDEN + KVD) * HIDDEN, HIDDEN, KVD, l & 7, l >> 3, tile, t, 1.0f);
    } else if (idx < 2560) {
        int l = idx - 1536;
        tcvt_tile(Wo, wot, HIDDEN, HIDDEN, l & 31, l >> 5, tile, t, 1.0f);
    } else if (idx < 2572) {
        int i = (idx - 2560) * 256 + t;
        if (i < QKVD) {
            float v = (i < HIDDEN) ? bq[i] * QSCALE
                                   : (i < HIDDEN + KVD ? bk[i - HIDDEN] : bv[i - HIDDEN - KVD]);
            bqkv[i] = v;
        }
    } else {
        // x cvt: 8192 blocks cover exactly BSZ*HIDDEN/4 float4s
        int i = (idx - 2572) * 256 + t;
        float4 f = ((const float4*)x)[i];
        bfx4 o = {(__bf16)f.x, (__bf16)f.y, (__bf16)f.z, (__bf16)f.w};
        *(bfx4*)(xb + (size_t)i * 4) = o;
    }
}

// ------- GEMM: C[M,N] = A[M,K] * Bt[N,K]^T + bias, 128x128 tile, 16x16x32 MFMA --------
// Champion structure (R7, (256,3)): 1-barrier dbuf K-loop + DMA prefetch, XOR staging
// swizzle, conflict-free fragment reads. (32x32x16 and (256,4) variants both tested
// and regressed — the binding constraint is the barrier-drain structure.)
// VSPLIT (gemm1 only): V-column tiles (n0 >= HIDDEN+KVD, 128-aligned so whole-block
// uniform) write TRANSPOSED into vt [B*NKV][HD][SEQ] — replaces the transpose_v kernel.
// Per (i,j) a thread's 4 acc values are 4 consecutive seq rows at one V-col -> bfx4.
template <bool OUT_BF16, bool VSPLIT>
__global__ __launch_bounds__(256, 3) void gemm128(const __bf16* __restrict__ A,
                                                  const __bf16* __restrict__ Bt,
                                                  const float* __restrict__ bias,
                                                  void* __restrict__ C,
                                                  __bf16* __restrict__ vt,
                                                  int M, int N, int K) {
    __shared__ __align__(16) __bf16 As[2][128 * 32];
    __shared__ __align__(16) __bf16 Bs[2][128 * 32];
    int t = threadIdx.x;
    int w = t >> 6, lane = t & 63;
    int lrow = lane & 15, quad = lane >> 4;
    long m0 = (long)blockIdx.y * 128, n0 = (long)blockIdx.x * 128;
    int wr = (w >> 1) * 64, wc = (w & 1) * 64;
    f32x4 acc[4][4] = {};
    int srow = t >> 2, scol = (((t & 3) ^ ((t >> 3) & 3))) * 8;  // staging swizzle
    int sA = (lrow >> 1) & 3;                                    // read-side selector
    const __bf16* Ag = A + (m0 + srow) * (long)K + scol;
    const __bf16* Bg = Bt + (n0 + srow) * (long)K + scol;
#define STAGE_G(kb, buf)                                                      \
    {                                                                         \
        _Pragma("unroll") for (int c = 0; c < 2; ++c) {                       \
            gl_lds16(Ag + (long)c * 64 * K + (kb), &As[buf][c * 2048 + w * 512]); \
            gl_lds16(Bg + (long)c * 64 * K + (kb), &Bs[buf][c * 2048 + w * 512]); \
        }                                                                     \
    }
    STAGE_G(0, 0);
    int nk = K >> 5;
    for (int it = 0; it < nk; ++it) {
        __syncthreads();  // drains prev-iter prefetch; all waves done with other buffer
        if (it + 1 < nk) STAGE_G((it + 1) * 32, (it + 1) & 1);
        const __bf16* Ab = &As[it & 1][0];
        const __bf16* Bb = &Bs[it & 1][0];
        bfx8 af[4], bfr[4];
#pragma unroll
        for (int i = 0; i < 4; ++i)
            af[i] = *(const bfx8*)&Ab[(wr + i * 16 + lrow) * 32 + ((quad ^ sA) * 8)];
#pragma unroll
        for (int j = 0; j < 4; ++j)
            bfr[j] = *(const bfx8*)&Bb[(wc + j * 16 + lrow) * 32 + ((quad ^ sA) * 8)];
#pragma unroll
        for (int i = 0; i < 4; ++i)
#pragma unroll
            for (int j = 0; j < 4; ++j)
                acc[i][j] = __builtin_amdgcn_mfma_f32_16x16x32_bf16(af[i], bfr[j], acc[i][j], 0, 0, 0);
    }
#undef STAGE_G
    if (VSPLIT && n0 >= (long)(HIDDEN + KVD)) {
        // V tile -> vt, transposed. b uniform per block (128 | 2048).
        int b = (int)(m0 >> 11);
        int s0 = (int)(m0 & 2047) + wr + quad * 4;
#pragma unroll
        for (int j = 0; j < 4; ++j) {
            int off = (int)(n0 - (HIDDEN + KVD)) + wc + j * 16 + lrow;  // 0..KVD-1
            float bv = bias[n0 + wc + j * 16 + lrow];
#pragma unroll
            for (int i = 0; i < 4; ++i) {
                bfx4 o4 = {(__bf16)(acc[i][j][0] + bv), (__bf16)(acc[i][j][1] + bv),
                           (__bf16)(acc[i][j][2] + bv), (__bf16)(acc[i][j][3] + bv)};
                *(bfx4*)&vt[((long)b * KVD + off) * SEQ + s0 + i * 16] = o4;
            }
        }
        return;
    }
#pragma unroll
    for (int j = 0; j < 4; ++j) {
        long col = n0 + wc + j * 16 + lrow;
        float bv = bias[col];
#pragma unroll
        for (int i = 0; i < 4; ++i) {
#pragma unroll
            for (int r = 0; r < 4; ++r) {
                long row = m0 + wr + i * 16 + quad * 4 + r;
                float val = acc[i][j][r] + bv;
                if (OUT_BF16)
                    ((__bf16*)C)[row * N + col] = (__bf16)val;
                else
                    ((float*)C)[row * N + col] = val;
            }
        }
    }
}

// ---------------- attention v8 (champion, frozen): 32 q/wave + T5 setprio ----------------
// 16 waves/CU is the empirically-best occupancy (64q/wave tested 3 ways: 93.5-94 µs vs
// 86.5 here). Full-rate x32 QK^T and PV, permlane-swap P^T repack, LDS dbuf DMA staging.
__global__ __launch_bounds__(256, 4) void attn(const __bf16* __restrict__ QKV,  // [BSZ,QKVD]
                                               const __bf16* __restrict__ Vt,   // [B*NKV][HD][SEQ]
                                               __bf16* __restrict__ O) {        // [BSZ,HIDDEN]
    __shared__ __align__(16) __bf16 Ks[2][64 * 64];
    __shared__ __align__(16) __bf16 Vs[2][64 * 64];
    int t = threadIdx.x;
    int w = t >> 6, lane = t & 63;
    int lrow = lane & 15, quad = lane >> 4;
    int qb = blockIdx.x, bh = blockIdx.y;
    int b = bh >> 5, h = bh & 31, kv = h >> 2;
    int q0 = qb * 128 + w * 32;  // first q-row of this wave

    // Q fragments (B operand: n=q=lane&15, k=quad*8+j)
    bfx8 qf[2][2];
#pragma unroll
    for (int i = 0; i < 2; ++i)
#pragma unroll
        for (int kk = 0; kk < 2; ++kk)
            qf[i][kk] = *(const bfx8*)(QKV + (long)(b * SEQ + q0 + i * 16 + lrow) * QKVD +
                                       h * HD + kk * 32 + quad * 8);

    int srow = t >> 2, scol = (((t & 3) ^ ((t >> 3) & 3))) * 8;  // staging swizzle
    int sA = (lrow >> 1) & 3;                                    // read-side selector
    const __bf16* kg = QKV + (long)(b * SEQ + srow) * QKVD + HIDDEN + kv * HD + scol;
    const __bf16* vg = Vt + ((long)(b * NKV + kv) * HD + srow) * SEQ + scol;
#define STAGE_KV(nb, buf)                                                          \
    {                                                                              \
        _Pragma("unroll") for (int c = 0; c < 2; ++c) {                            \
            gl_lds16(kg + (long)(nb)*QKVD + c * 32, &Ks[buf][c * 2048 + w * 512]); \
            gl_lds16(vg + (nb) + c * 32, &Vs[buf][c * 2048 + w * 512]);            \
        }                                                                          \
    }
    STAGE_KV(0, 0);

    f32x4 accO[4][2] = {};  // [dtile][qtile]; lane=q(lane&15), d = quad*4 + reg
    float lacc[2] = {0.f, 0.f};

    for (int it = 0; it < SEQ / 64; ++it) {
        __syncthreads();  // drains this chunk's DMA; all waves done with other buffer
        if (it + 1 < SEQ / 64) STAGE_KV((it + 1) * 64, (it + 1) & 1);
        const __bf16* Kb = &Ks[it & 1][0];
        const __bf16* Vb = &Vs[it & 1][0];
#pragma unroll
        for (int ch = 0; ch < 2; ++ch) {  // 32-key chunk = key tiles 2ch, 2ch+1
            f32x4 s2[2][2];               // [tile-in-pair][qtile]
#pragma unroll
            for (int tp = 0; tp < 2; ++tp) {
                int tt = ch * 2 + tp;
                bfx8 ka0 = *(const bfx8*)&Kb[tt * 512 + lrow * 32 + ((quad ^ sA) * 8)];
                bfx8 ka1 = *(const bfx8*)&Kb[2048 + tt * 512 + lrow * 32 + ((quad ^ sA) * 8)];
                __builtin_amdgcn_s_setprio(1);
#pragma unroll
                for (int i = 0; i < 2; ++i) {
                    f32x4 z = {};
                    z = __builtin_amdgcn_mfma_f32_16x16x32_bf16(ka0, qf[i][0], z, 0, 0, 0);
                    s2[tp][i] = __builtin_amdgcn_mfma_f32_16x16x32_bf16(ka1, qf[i][1], z, 0, 0, 0);
                }
                __builtin_amdgcn_s_setprio(0);
            }
            // exp2 + row-sum + pack P^T into x32 fragments (one per q-tile)
            bfx8 p8v[2];
#pragma unroll
            for (int i = 0; i < 2; ++i) {
                float pa0 = __builtin_amdgcn_exp2f(s2[0][i][0]);
                float pa1 = __builtin_amdgcn_exp2f(s2[0][i][1]);
                float pa2 = __builtin_amdgcn_exp2f(s2[0][i][2]);
                float pa3 = __builtin_amdgcn_exp2f(s2[0][i][3]);
                float pb0 = __builtin_amdgcn_exp2f(s2[1][i][0]);
                float pb1 = __builtin_amdgcn_exp2f(s2[1][i][1]);
                float pb2 = __builtin_amdgcn_exp2f(s2[1][i][2]);
                float pb3 = __builtin_amdgcn_exp2f(s2[1][i][3]);
                lacc[i] += ((pa0 + pa1) + (pa2 + pa3)) + ((pb0 + pb1) + (pb2 + pb3));
                unsigned int A0 = pk2(pa0, pa1), A1 = pk2(pa2, pa3);
                unsigned int B0 = pk2(pb0, pb1), B1 = pk2(pb2, pb3);
                asm("v_permlane32_swap_b32 %0, %1" : "+v"(A0), "+v"(B0));
                asm("v_permlane16_swap_b32 %0, %1" : "+v"(A0), "+v"(B0));
                asm("v_permlane32_swap_b32 %0, %1" : "+v"(A1), "+v"(B1));
                asm("v_permlane16_swap_b32 %0, %1" : "+v"(A1), "+v"(B1));
                ux4 pw = {A0, A1, B0, B1};  // = {w0, w1, w2, w3}
                p8v[i] = __builtin_bit_cast(bfx8, pw);
            }
            // V a-frags: m=d=lane&15, k = quad*8+j -> same b128 pattern as K
#pragma unroll
            for (int dt = 0; dt < 4; ++dt) {
                bfx8 va = *(const bfx8*)&Vb[ch * 2048 + (dt * 16 + lrow) * 32 + ((quad ^ sA) * 8)];
                __builtin_amdgcn_s_setprio(1);
#pragma unroll
                for (int i = 0; i < 2; ++i)
                    accO[dt][i] = __builtin_amdgcn_mfma_f32_16x16x32_bf16(va, p8v[i], accO[dt][i], 0, 0, 0);
                __builtin_amdgcn_s_setprio(0);
            }
        }
    }
    // ---- epilogue: cross-quad l reduction, normalize, packed b64 stores ----
    float inv[2];
#pragma unroll
    for (int i = 0; i < 2; ++i) {
        float l = lacc[i];
        l += __shfl_xor(l, 16);
        l += __shfl_xor(l, 32);
        inv[i] = 1.0f / l;
    }
#pragma unroll
    for (int i = 0; i < 2; ++i) {
        long row = (long)(b * SEQ + q0 + i * 16 + lrow);
#pragma unroll
        for (int dt = 0; dt < 4; ++dt) {
            bfx4 o4 = {(__bf16)(accO[dt][i][0] * inv[i]), (__bf16)(accO[dt][i][1] * inv[i]),
                       (__bf16)(accO[dt][i][2] * inv[i]), (__bf16)(accO[dt][i][3] * inv[i])};
            *(bfx4*)&O[row * HIDDEN + h * HD + dt * 16 + quad * 4] = o4;
        }
    }
#undef STAGE_KV
}

extern "C" void kernel_launch(void* const* d_in, const int* in_sizes, int n_in,
                              void* d_out, int out_size, void* d_ws, size_t ws_size,
                              hipStream_t stream) {
    const float* x  = (const float*)d_in[0];
    const float* Wq = (const float*)d_in[1];
    const float* bq = (const float*)d_in[2];
    const float* Wk = (const float*)d_in[3];
    const float* bk = (const float*)d_in[4];
    const float* Wv = (const float*)d_in[5];
    const float* bv = (const float*)d_in[6];
    const float* Wo = (const float*)d_in[7];
    const float* bo = (const float*)d_in[8];
    float* out = (float*)d_out;

    __bf16* ws    = (__bf16*)d_ws;
    __bf16* xb    = ws;                                   // [BSZ, HIDDEN]
    __bf16* wqkvt = xb + (size_t)BSZ * HIDDEN;            // [QKVD, HIDDEN] (N,K)
    __bf16* wot   = wqkvt + (size_t)QKVD * HIDDEN;        // [HIDDEN, HIDDEN]
    __bf16* qkv   = wot + (size_t)HIDDEN * HIDDEN;        // [BSZ, QKVD]
    __bf16* vt_   = qkv + (size_t)BSZ * QKVD;             // [B*NKV][HD][SEQ]
    __bf16* ab_   = vt_ + (size_t)BSZ * KVD;              // [BSZ, HIDDEN]
    float*  bqkv  = (float*)(ab_ + (size_t)BSZ * HIDDEN); // [QKVD]

    prep<<<2572 + 8192, 256, 0, stream>>>(x, Wq, Wk, Wv, Wo, bq, bk, bv,
                                          xb, wqkvt, wot, bqkv);

    gemm128<true, true><<<dim3(QKVD / 128, BSZ / 128), 256, 0, stream>>>(
        xb, wqkvt, bqkv, qkv, vt_, BSZ, QKVD, HIDDEN);

    attn<<<dim3(SEQ / 128, BATCH * NHEADS), 256, 0, stream>>>(qkv, vt_, ab_);

    gemm128<false, false><<<dim3(HIDDEN / 128, BSZ / 128), 256, 0, stream>>>(
        ab_, wot, (const float*)bo, out, nullptr, BSZ, HIDDEN, HIDDEN);
}

// Round 12
// 304.719 us; speedup vs baseline: 1.0732x; 1.0261x over previous
//
#include <hip/hip_runtime.h>

#define HIDDEN 2048
#define NHEADS 32
#define NKV 8
#define HD 64
#define BATCH 2
#define SEQ 2048
#define KVD 512    // NKV*HD
#define BSZ 4096   // BATCH*SEQ
#define QKVD 3072  // HIDDEN + 2*KVD

typedef __bf16 bfx8 __attribute__((ext_vector_type(8)));
typedef __bf16 bfx4 __attribute__((ext_vector_type(4)));
typedef __bf16 bfx2 __attribute__((ext_vector_type(2)));
typedef float f32x4 __attribute__((ext_vector_type(4)));
typedef unsigned int ux4 __attribute__((ext_vector_type(4)));

// Q pre-scale folded into Wq/bq: exp(s/8) = 2^(s*0.125*log2e)
#define QSCALE 0.1803368801111204f

// async global->LDS, 16B per lane. LDS dest is wave-uniform base; HW adds lane*16.
__device__ __forceinline__ void gl_lds16(const __bf16* g, __bf16* l) {
    __builtin_amdgcn_global_load_lds(
        (const __attribute__((address_space(1))) unsigned int*)g,
        (__attribute__((address_space(3))) unsigned int*)l, 16, 0, 0);
}

// pack two f32 -> one u32 of 2x bf16 (compiler emits v_cvt_pk_bf16_f32)
__device__ __forceinline__ unsigned int pk2(float lo, float hi) {
    bfx2 v = {(__bf16)lo, (__bf16)hi};
    return __builtin_bit_cast(unsigned int, v);
}

// ------------- one 64x64 tile: src f32 [R,C] -> dst bf16 [C,R], *mul -------------
__device__ __forceinline__ void tcvt_tile(const float* __restrict__ src,
                                          __bf16* __restrict__ dst,
                                          int R, int C, int tx, int ty,
                                          float (*tile)[65], int t, float mul) {
    int br = ty * 64, bc = tx * 64;
    {
        int r = t >> 4, c = (t & 15) * 4;
#pragma unroll
        for (int i = 0; i < 4; ++i) {
            float4 v = *(const float4*)(&src[(long)(br + r + i * 16) * C + bc + c]);
            tile[r + i * 16][c + 0] = v.x * mul;
            tile[r + i * 16][c + 1] = v.y * mul;
            tile[r + i * 16][c + 2] = v.z * mul;
            tile[r + i * 16][c + 3] = v.w * mul;
        }
    }
    __syncthreads();
    {
        int d = t >> 2, tt0 = (t & 3) * 16;
        bfx8 o0, o1;
#pragma unroll
        for (int j = 0; j < 8; ++j) o0[j] = (__bf16)tile[tt0 + j][d];
#pragma unroll
        for (int j = 0; j < 8; ++j) o1[j] = (__bf16)tile[tt0 + 8 + j][d];
        *(bfx8*)(&dst[(long)(bc + d) * R + br + tt0]) = o0;
        *(bfx8*)(&dst[(long)(bc + d) * R + br + tt0 + 8]) = o1;
    }
}

// --- fused prep: 4 weight transposes + bias concat + x f32->bf16 cvt, one launch ---
__global__ __launch_bounds__(256) void prep(const float* __restrict__ x,
                                            const float* __restrict__ Wq,
                                            const float* __restrict__ Wk,
                                            const float* __restrict__ Wv,
                                            const float* __restrict__ Wo,
                                            const float* __restrict__ bq,
                                            const float* __restrict__ bk,
                                            const float* __restrict__ bv,
                                            __bf16* __restrict__ xb,
                                            __bf16* __restrict__ wqkvt,
                                            __bf16* __restrict__ wot,
                                            float* __restrict__ bqkv) {
    __shared__ float tile[64][65];
    int idx = blockIdx.x, t = threadIdx.x;
    if (idx < 1024) {
        tcvt_tile(Wq, wqkvt, HIDDEN, HIDDEN, idx & 31, idx >> 5, tile, t, QSCALE);
    } else if (idx < 1280) {
        int l = idx - 1024;
        tcvt_tile(Wk, wqkvt + (size_t)HIDDEN * HIDDEN, HIDDEN, KVD, l & 7, l >> 3, tile, t, 1.0f);
    } else if (idx < 1536) {
        int l = idx - 1280;
        tcvt_tile(Wv, wqkvt + (size_t)(HIDDEN + KVD) * HIDDEN, HIDDEN, KVD, l & 7, l >> 3, tile, t, 1.0f);
    } else if (idx < 2560) {
        int l = idx - 1536;
        tcvt_tile(Wo, wot, HIDDEN, HIDDEN, l & 31, l >> 5, tile, t, 1.0f);
    } else if (idx < 2572) {
        int i = (idx - 2560) * 256 + t;
        if (i < QKVD) {
            float v = (i < HIDDEN) ? bq[i] * QSCALE
                                   : (i < HIDDEN + KVD ? bk[i - HIDDEN] : bv[i - HIDDEN - KVD]);
            bqkv[i] = v;
        }
    } else {
        // x cvt: 8192 blocks cover exactly BSZ*HIDDEN/4 float4s
        int i = (idx - 2572) * 256 + t;
        float4 f = ((const float4*)x)[i];
        bfx4 o = {(__bf16)f.x, (__bf16)f.y, (__bf16)f.z, (__bf16)f.w};
        *(bfx4*)(xb + (size_t)i * 4) = o;
    }
}

// ------- GEMM: C[M,N] = A[M,K] * Bt[N,K]^T + bias, 128x128 tile, 16x16x32 MFMA --------
// Champion structure (R7, (256,3)): 1-barrier dbuf K-loop + DMA prefetch, XOR staging
// swizzle, conflict-free fragment reads. (32x32x16 and (256,4) variants both tested
// and regressed — the binding constraint is the barrier-drain structure.)
// R12: T1 XCD-aware chunked block swizzle (bijective: both grids %8==0). Each XCD gets
// a contiguous tile range -> its 4MB L2 holds ~4 A-panels instead of streaming all of
// A+B (default round-robin spreads panel-sharing neighbors across 8 XCDs).
// VSPLIT (gemm1 only): V-column tiles (n0 >= HIDDEN+KVD, 128-aligned so whole-block
// uniform) write TRANSPOSED into vt [B*NKV][HD][SEQ] — replaces the transpose_v kernel.
template <bool OUT_BF16, bool VSPLIT>
__global__ __launch_bounds__(256, 3) void gemm128(const __bf16* __restrict__ A,
                                                  const __bf16* __restrict__ Bt,
                                                  const float* __restrict__ bias,
                                                  void* __restrict__ C,
                                                  __bf16* __restrict__ vt,
                                                  int M, int N, int K) {
    __shared__ __align__(16) __bf16 As[2][128 * 32];
    __shared__ __align__(16) __bf16 Bs[2][128 * 32];
    int t = threadIdx.x;
    int w = t >> 6, lane = t & 63;
    int lrow = lane & 15, quad = lane >> 4;
    // T1 XCD swizzle: wgid -> (xcd = wgid&7) gets contiguous chunk [xcd*q, (xcd+1)*q)
    int nbx = gridDim.x, nwg = nbx * gridDim.y;
    int wgid = blockIdx.y * nbx + blockIdx.x;
    int swz = (wgid & 7) * (nwg >> 3) + (wgid >> 3);
    long m0 = (long)(swz / nbx) * 128, n0 = (long)(swz % nbx) * 128;
    int wr = (w >> 1) * 64, wc = (w & 1) * 64;
    f32x4 acc[4][4] = {};
    int srow = t >> 2, scol = (((t & 3) ^ ((t >> 3) & 3))) * 8;  // staging swizzle
    int sA = (lrow >> 1) & 3;                                    // read-side selector
    const __bf16* Ag = A + (m0 + srow) * (long)K + scol;
    const __bf16* Bg = Bt + (n0 + srow) * (long)K + scol;
#define STAGE_G(kb, buf)                                                      \
    {                                                                         \
        _Pragma("unroll") for (int c = 0; c < 2; ++c) {                       \
            gl_lds16(Ag + (long)c * 64 * K + (kb), &As[buf][c * 2048 + w * 512]); \
            gl_lds16(Bg + (long)c * 64 * K + (kb), &Bs[buf][c * 2048 + w * 512]); \
        }                                                                     \
    }
    STAGE_G(0, 0);
    int nk = K >> 5;
    for (int it = 0; it < nk; ++it) {
        __syncthreads();  // drains prev-iter prefetch; all waves done with other buffer
        if (it + 1 < nk) STAGE_G((it + 1) * 32, (it + 1) & 1);
        const __bf16* Ab = &As[it & 1][0];
        const __bf16* Bb = &Bs[it & 1][0];
        bfx8 af[4], bfr[4];
#pragma unroll
        for (int i = 0; i < 4; ++i)
            af[i] = *(const bfx8*)&Ab[(wr + i * 16 + lrow) * 32 + ((quad ^ sA) * 8)];
#pragma unroll
        for (int j = 0; j < 4; ++j)
            bfr[j] = *(const bfx8*)&Bb[(wc + j * 16 + lrow) * 32 + ((quad ^ sA) * 8)];
#pragma unroll
        for (int i = 0; i < 4; ++i)
#pragma unroll
            for (int j = 0; j < 4; ++j)
                acc[i][j] = __builtin_amdgcn_mfma_f32_16x16x32_bf16(af[i], bfr[j], acc[i][j], 0, 0, 0);
    }
#undef STAGE_G
    if (VSPLIT && n0 >= (long)(HIDDEN + KVD)) {
        // V tile -> vt, transposed. b uniform per block (128 | 2048).
        int b = (int)(m0 >> 11);
        int s0 = (int)(m0 & 2047) + wr + quad * 4;
#pragma unroll
        for (int j = 0; j < 4; ++j) {
            int off = (int)(n0 - (HIDDEN + KVD)) + wc + j * 16 + lrow;  // 0..KVD-1
            float bv = bias[n0 + wc + j * 16 + lrow];
#pragma unroll
            for (int i = 0; i < 4; ++i) {
                bfx4 o4 = {(__bf16)(acc[i][j][0] + bv), (__bf16)(acc[i][j][1] + bv),
                           (__bf16)(acc[i][j][2] + bv), (__bf16)(acc[i][j][3] + bv)};
                *(bfx4*)&vt[((long)b * KVD + off) * SEQ + s0 + i * 16] = o4;
            }
        }
        return;
    }
#pragma unroll
    for (int j = 0; j < 4; ++j) {
        long col = n0 + wc + j * 16 + lrow;
        float bv = bias[col];
#pragma unroll
        for (int i = 0; i < 4; ++i) {
#pragma unroll
            for (int r = 0; r < 4; ++r) {
                long row = m0 + wr + i * 16 + quad * 4 + r;
                float val = acc[i][j][r] + bv;
                if (OUT_BF16)
                    ((__bf16*)C)[row * N + col] = (__bf16)val;
                else
                    ((float*)C)[row * N + col] = val;
            }
        }
    }
}

// ---------------- attention v8 (champion, frozen): 32 q/wave + T5 setprio ----------------
// 16 waves/CU is the empirically-best occupancy (64q/wave tested 3 ways: 93.5-94 µs vs
// 86.5 here). Full-rate x32 QK^T and PV, permlane-swap P^T repack, LDS dbuf DMA staging.
__global__ __launch_bounds__(256, 4) void attn(const __bf16* __restrict__ QKV,  // [BSZ,QKVD]
                                               const __bf16* __restrict__ Vt,   // [B*NKV][HD][SEQ]
                                               __bf16* __restrict__ O) {        // [BSZ,HIDDEN]
    __shared__ __align__(16) __bf16 Ks[2][64 * 64];
    __shared__ __align__(16) __bf16 Vs[2][64 * 64];
    int t = threadIdx.x;
    int w = t >> 6, lane = t & 63;
    int lrow = lane & 15, quad = lane >> 4;
    int qb = blockIdx.x, bh = blockIdx.y;
    int b = bh >> 5, h = bh & 31, kv = h >> 2;
    int q0 = qb * 128 + w * 32;  // first q-row of this wave

    // Q fragments (B operand: n=q=lane&15, k=quad*8+j)
    bfx8 qf[2][2];
#pragma unroll
    for (int i = 0; i < 2; ++i)
#pragma unroll
        for (int kk = 0; kk < 2; ++kk)
            qf[i][kk] = *(const bfx8*)(QKV + (long)(b * SEQ + q0 + i * 16 + lrow) * QKVD +
                                       h * HD + kk * 32 + quad * 8);

    int srow = t >> 2, scol = (((t & 3) ^ ((t >> 3) & 3))) * 8;  // staging swizzle
    int sA = (lrow >> 1) & 3;                                    // read-side selector
    const __bf16* kg = QKV + (long)(b * SEQ + srow) * QKVD + HIDDEN + kv * HD + scol;
    const __bf16* vg = Vt + ((long)(b * NKV + kv) * HD + srow) * SEQ + scol;
#define STAGE_KV(nb, buf)                                                          \
    {                                                                              \
        _Pragma("unroll") for (int c = 0; c < 2; ++c) {                            \
            gl_lds16(kg + (long)(nb)*QKVD + c * 32, &Ks[buf][c * 2048 + w * 512]); \
            gl_lds16(vg + (nb) + c * 32, &Vs[buf][c * 2048 + w * 512]);            \
        }                                                                          \
    }
    STAGE_KV(0, 0);

    f32x4 accO[4][2] = {};  // [dtile][qtile]; lane=q(lane&15), d = quad*4 + reg
    float lacc[2] = {0.f, 0.f};

    for (int it = 0; it < SEQ / 64; ++it) {
        __syncthreads();  // drains this chunk's DMA; all waves done with other buffer
        if (it + 1 < SEQ / 64) STAGE_KV((it + 1) * 64, (it + 1) & 1);
        const __bf16* Kb = &Ks[it & 1][0];
        const __bf16* Vb = &Vs[it & 1][0];
#pragma unroll
        for (int ch = 0; ch < 2; ++ch) {  // 32-key chunk = key tiles 2ch, 2ch+1
            f32x4 s2[2][2];               // [tile-in-pair][qtile]
#pragma unroll
            for (int tp = 0; tp < 2; ++tp) {
                int tt = ch * 2 + tp;
                bfx8 ka0 = *(const bfx8*)&Kb[tt * 512 + lrow * 32 + ((quad ^ sA) * 8)];
                bfx8 ka1 = *(const bfx8*)&Kb[2048 + tt * 512 + lrow * 32 + ((quad ^ sA) * 8)];
                __builtin_amdgcn_s_setprio(1);
#pragma unroll
                for (int i = 0; i < 2; ++i) {
                    f32x4 z = {};
                    z = __builtin_amdgcn_mfma_f32_16x16x32_bf16(ka0, qf[i][0], z, 0, 0, 0);
                    s2[tp][i] = __builtin_amdgcn_mfma_f32_16x16x32_bf16(ka1, qf[i][1], z, 0, 0, 0);
                }
                __builtin_amdgcn_s_setprio(0);
            }
            // exp2 + row-sum + pack P^T into x32 fragments (one per q-tile)
            bfx8 p8v[2];
#pragma unroll
            for (int i = 0; i < 2; ++i) {
                float pa0 = __builtin_amdgcn_exp2f(s2[0][i][0]);
                float pa1 = __builtin_amdgcn_exp2f(s2[0][i][1]);
                float pa2 = __builtin_amdgcn_exp2f(s2[0][i][2]);
                float pa3 = __builtin_amdgcn_exp2f(s2[0][i][3]);
                float pb0 = __builtin_amdgcn_exp2f(s2[1][i][0]);
                float pb1 = __builtin_amdgcn_exp2f(s2[1][i][1]);
                float pb2 = __builtin_amdgcn_exp2f(s2[1][i][2]);
                float pb3 = __builtin_amdgcn_exp2f(s2[1][i][3]);
                lacc[i] += ((pa0 + pa1) + (pa2 + pa3)) + ((pb0 + pb1) + (pb2 + pb3));
                unsigned int A0 = pk2(pa0, pa1), A1 = pk2(pa2, pa3);
                unsigned int B0 = pk2(pb0, pb1), B1 = pk2(pb2, pb3);
                asm("v_permlane32_swap_b32 %0, %1" : "+v"(A0), "+v"(B0));
                asm("v_permlane16_swap_b32 %0, %1" : "+v"(A0), "+v"(B0));
                asm("v_permlane32_swap_b32 %0, %1" : "+v"(A1), "+v"(B1));
                asm("v_permlane16_swap_b32 %0, %1" : "+v"(A1), "+v"(B1));
                ux4 pw = {A0, A1, B0, B1};  // = {w0, w1, w2, w3}
                p8v[i] = __builtin_bit_cast(bfx8, pw);
            }
            // V a-frags: m=d=lane&15, k = quad*8+j -> same b128 pattern as K
#pragma unroll
            for (int dt = 0; dt < 4; ++dt) {
                bfx8 va = *(const bfx8*)&Vb[ch * 2048 + (dt * 16 + lrow) * 32 + ((quad ^ sA) * 8)];
                __builtin_amdgcn_s_setprio(1);
#pragma unroll
                for (int i = 0; i < 2; ++i)
                    accO[dt][i] = __builtin_amdgcn_mfma_f32_16x16x32_bf16(va, p8v[i], accO[dt][i], 0, 0, 0);
                __builtin_amdgcn_s_setprio(0);
            }
        }
    }
    // ---- epilogue: cross-quad l reduction, normalize, packed b64 stores ----
    float inv[2];
#pragma unroll
    for (int i = 0; i < 2; ++i) {
        float l = lacc[i];
        l += __shfl_xor(l, 16);
        l += __shfl_xor(l, 32);
        inv[i] = 1.0f / l;
    }
#pragma unroll
    for (int i = 0; i < 2; ++i) {
        long row = (long)(b * SEQ + q0 + i * 16 + lrow);
#pragma unroll
        for (int dt = 0; dt < 4; ++dt) {
            bfx4 o4 = {(__bf16)(accO[dt][i][0] * inv[i]), (__bf16)(accO[dt][i][1] * inv[i]),
                       (__bf16)(accO[dt][i][2] * inv[i]), (__bf16)(accO[dt][i][3] * inv[i])};
            *(bfx4*)&O[row * HIDDEN + h * HD + dt * 16 + quad * 4] = o4;
        }
    }
#undef STAGE_KV
}

extern "C" void kernel_launch(void* const* d_in, const int* in_sizes, int n_in,
                              void* d_out, int out_size, void* d_ws, size_t ws_size,
                              hipStream_t stream) {
    const float* x  = (const float*)d_in[0];
    const float* Wq = (const float*)d_in[1];
    const float* bq = (const float*)d_in[2];
    const float* Wk = (const float*)d_in[3];
    const float* bk = (const float*)d_in[4];
    const float* Wv = (const float*)d_in[5];
    const float* bv = (const float*)d_in[6];
    const float* Wo = (const float*)d_in[7];
    const float* bo = (const float*)d_in[8];
    float* out = (float*)d_out;

    __bf16* ws    = (__bf16*)d_ws;
    __bf16* xb    = ws;                                   // [BSZ, HIDDEN]
    __bf16* wqkvt = xb + (size_t)BSZ * HIDDEN;            // [QKVD, HIDDEN] (N,K)
    __bf16* wot   = wqkvt + (size_t)QKVD * HIDDEN;        // [HIDDEN, HIDDEN]
    __bf16* qkv   = wot + (size_t)HIDDEN * HIDDEN;        // [BSZ, QKVD]
    __bf16* vt_   = qkv + (size_t)BSZ * QKVD;             // [B*NKV][HD][SEQ]
    __bf16* ab_   = vt_ + (size_t)BSZ * KVD;              // [BSZ, HIDDEN]
    float*  bqkv  = (float*)(ab_ + (size_t)BSZ * HIDDEN); // [QKVD]

    prep<<<2572 + 8192, 256, 0, stream>>>(x, Wq, Wk, Wv, Wo, bq, bk, bv,
                                          xb, wqkvt, wot, bqkv);

    gemm128<true, true><<<dim3(QKVD / 128, BSZ / 128), 256, 0, stream>>>(
        xb, wqkvt, bqkv, qkv, vt_, BSZ, QKVD, HIDDEN);

    attn<<<dim3(SEQ / 128, BATCH * NHEADS), 256, 0, stream>>>(qkv, vt_, ab_);

    gemm128<false, false><<<dim3(HIDDEN / 128, BSZ / 128), 256, 0, stream>>>(
        ab_, wot, (const float*)bo, out, nullptr, BSZ, HIDDEN, HIDDEN);
}